// Round 1
// baseline (1337.868 us; speedup 1.0000x reference)
//
#include <hip/hip_runtime.h>
#include <math.h>

// Problem constants
#define BB 8
#define TT 512
#define DD 768
#define HH 8
#define HDIM 96

typedef short s16x8 __attribute__((ext_vector_type(8)));
typedef float f32x4 __attribute__((ext_vector_type(4)));

__device__ inline unsigned short f2bf(float f) {
    union { float f; unsigned u; } v; v.f = f;
    unsigned u = v.u;
    unsigned r = (u + 0x7fffu + ((u >> 16) & 1u)) >> 16;
    return (unsigned short)r;
}

__device__ inline float gelu_exact(float x) {
    return 0.5f * x * (1.0f + erff(x * 0.70710678118654752440f));
}

// ---------------------------------------------------------------------------
// Generic batched GEMM: C[z] = alpha * A[z] * op(B[z]) (+bias) (gelu?) (+resid)
//   A is [M,K] row-major, lda
//   TRANSB=1: B is [N,K] row-major (ldb over n)  -> C = A * B^T
//   TRANSB=0: B is [K,N] row-major (ldb over k)  -> C = A * B
//   z = zb*Hd + zh;  A off = zb*sAb + zh*sAh;  B off = bidx? bidx[zb]*sBexp : 0
//                     plus zb*sBb + zh*sBh;  C off = zb*sCb + zh*sCh
// Block tile 64x64, K-tile 32, 4 waves each computing 32x32 via 2x2 MFMA 16x16x32.
// ---------------------------------------------------------------------------
template<int TRANSB>
__global__ __launch_bounds__(256) void gemm_kernel(
    const float* __restrict__ A, long long sAb, long long sAh, int lda,
    const float* __restrict__ Bmat, long long sBb, long long sBh, int ldb,
    const int* __restrict__ bidx, long long sBexp,
    float* __restrict__ C, long long sCb, long long sCh, int ldc,
    const float* __restrict__ bias, long long sBiasExp,
    const float* __restrict__ resid, long long sResB, int ldr,
    float alpha, int act, int M, int N, int K, int Hd)
{
    int z = blockIdx.z;
    int zb = z / Hd;
    int zh = z - zb * Hd;
    const float* Ab = A + zb * sAb + zh * sAh;
    long long boff = zb * sBb + zh * sBh;
    if (bidx) boff += (long long)bidx[zb] * sBexp;
    const float* Bb = Bmat + boff;
    float* Cb = C + zb * sCb + zh * sCh;
    const float* biasb = bias ? (bias + (bidx ? (long long)bidx[zb] * sBiasExp : 0)) : nullptr;
    const float* residb = resid ? (resid + zb * sResB) : nullptr;

    int n0 = blockIdx.x * 64;
    int m0 = blockIdx.y * 64;

    // LDS tiles: 64 rows x 32 bf16, row stride 40 shorts (80 B: 16B-aligned, 2-way banks)
    __shared__ __align__(16) unsigned short As[64 * 40];
    __shared__ __align__(16) unsigned short Bs[64 * 40];

    int tid = threadIdx.x;
    int wave = tid >> 6;
    int lane = tid & 63;
    int wi = wave & 1, wj = wave >> 1;
    int lrow = lane & 15;
    int lk = (lane >> 4) * 8;

    f32x4 acc[2][2];
    #pragma unroll
    for (int i = 0; i < 2; i++)
        #pragma unroll
        for (int j = 0; j < 2; j++)
            acc[i][j] = (f32x4){0.f, 0.f, 0.f, 0.f};

    int nK = K >> 5;
    for (int kt = 0; kt < nK; ++kt) {
        int k0 = kt << 5;
        __syncthreads();
        // stage A: 64x32 f32 -> bf16. slot s: row=s>>3, col=(s&7)*4
        #pragma unroll
        for (int half = 0; half < 2; ++half) {
            int s = tid + half * 256;
            int r = s >> 3, cs = (s & 7) * 4;
            const float* src = Ab + (long long)(m0 + r) * lda + k0 + cs;
            float4 v = *(const float4*)src;
            unsigned short* dst = &As[r * 40 + cs];
            dst[0] = f2bf(v.x); dst[1] = f2bf(v.y); dst[2] = f2bf(v.z); dst[3] = f2bf(v.w);
        }
        if (TRANSB) {
            #pragma unroll
            for (int half = 0; half < 2; ++half) {
                int s = tid + half * 256;
                int r = s >> 3, cs = (s & 7) * 4;
                int n = n0 + r;
                unsigned short* dst = &Bs[r * 40 + cs];
                if (n < N) {
                    const float* src = Bb + (long long)n * ldb + k0 + cs;
                    float4 v = *(const float4*)src;
                    dst[0] = f2bf(v.x); dst[1] = f2bf(v.y); dst[2] = f2bf(v.z); dst[3] = f2bf(v.w);
                } else {
                    dst[0] = 0; dst[1] = 0; dst[2] = 0; dst[3] = 0;
                }
            }
        } else {
            // B[k][n] -> Bs[n][k] transpose-on-stage. slot s: k=s>>4, n=(s&15)*4
            #pragma unroll
            for (int half = 0; half < 2; ++half) {
                int s = tid + half * 256;
                int k = s >> 4, ns = (s & 15) * 4;
                const float* src = Bb + (long long)(k0 + k) * ldb + n0 + ns;
                #pragma unroll
                for (int j = 0; j < 4; ++j) {
                    float v = (n0 + ns + j < N) ? src[j] : 0.0f;
                    Bs[(ns + j) * 40 + k] = f2bf(v);
                }
            }
        }
        __syncthreads();

        s16x8 afrag[2], bfrag[2];
        #pragma unroll
        for (int i = 0; i < 2; i++)
            afrag[i] = *(const s16x8*)&As[(wi * 32 + i * 16 + lrow) * 40 + lk];
        #pragma unroll
        for (int j = 0; j < 2; j++)
            bfrag[j] = *(const s16x8*)&Bs[(wj * 32 + j * 16 + lrow) * 40 + lk];
        #pragma unroll
        for (int i = 0; i < 2; i++)
            #pragma unroll
            for (int j = 0; j < 2; j++)
                acc[i][j] = __builtin_amdgcn_mfma_f32_16x16x32_bf16(afrag[i], bfrag[j], acc[i][j], 0, 0, 0);
    }

    // epilogue: C/D layout col=lane&15, row=(lane>>4)*4+reg
    int col16 = lane & 15;
    int rquad = (lane >> 4) * 4;
    #pragma unroll
    for (int i = 0; i < 2; i++) {
        #pragma unroll
        for (int j = 0; j < 2; j++) {
            int n = n0 + wj * 32 + j * 16 + col16;
            if (n >= N) continue;
            float bv = biasb ? biasb[n] : 0.0f;
            #pragma unroll
            for (int r = 0; r < 4; r++) {
                int m = m0 + wi * 32 + i * 16 + rquad + r;
                float v = alpha * acc[i][j][r] + bv;
                if (act == 1) v = gelu_exact(v);
                if (residb) v += residb[(long long)m * ldr + n];
                Cb[(long long)m * ldc + n] = v;
            }
        }
    }
}

// ---------------------------------------------------------------------------
// Row softmax over T=512 with optional causal mask (col > row masked).
// S layout: [64][512][512]
// ---------------------------------------------------------------------------
__global__ __launch_bounds__(256) void softmax_kernel(float* __restrict__ S, int causal)
{
    int r = blockIdx.x;
    long long z = blockIdx.y;
    float* row = S + z * (long long)TT * TT + (long long)r * TT;
    int t = threadIdx.x;
    __shared__ float red[256];
    float v0 = row[t], v1 = row[t + 256];
    if (causal) {
        if (t > r) v0 = -INFINITY;
        if (t + 256 > r) v1 = -INFINITY;
    }
    float mx = fmaxf(v0, v1);
    red[t] = mx; __syncthreads();
    for (int s = 128; s > 0; s >>= 1) {
        if (t < s) red[t] = fmaxf(red[t], red[t + s]);
        __syncthreads();
    }
    mx = red[0];
    __syncthreads();
    float e0 = expf(v0 - mx), e1 = expf(v1 - mx);
    red[t] = e0 + e1; __syncthreads();
    for (int s = 128; s > 0; s >>= 1) {
        if (t < s) red[t] += red[t + s];
        __syncthreads();
    }
    float inv = 1.0f / red[0];
    row[t] = e0 * inv;
    row[t + 256] = e1 * inv;
}

// ---------------------------------------------------------------------------
// LayerNorm over last dim (768). One block per row.
// ---------------------------------------------------------------------------
__global__ __launch_bounds__(256) void ln_kernel(
    const float* __restrict__ x, const float* __restrict__ g,
    const float* __restrict__ b, float* __restrict__ out)
{
    long long row = blockIdx.x;
    const float* xr = x + row * DD;
    float* orow = out + row * DD;
    int t = threadIdx.x;
    float vals[3];
    float s = 0.f, ss = 0.f;
    #pragma unroll
    for (int i = 0; i < 3; i++) {
        float v = xr[t + i * 256];
        vals[i] = v; s += v; ss += v * v;
    }
    __shared__ float rs[256], rss[256];
    rs[t] = s; rss[t] = ss; __syncthreads();
    for (int k = 128; k > 0; k >>= 1) {
        if (t < k) { rs[t] += rs[t + k]; rss[t] += rss[t + k]; }
        __syncthreads();
    }
    float mean = rs[0] * (1.0f / DD);
    float var = rss[0] * (1.0f / DD) - mean * mean;
    float inv = rsqrtf(var + 1e-5f);
    #pragma unroll
    for (int i = 0; i < 3; i++) {
        int d = t + i * 256;
        orow[d] = (vals[i] - mean) * inv * g[d] + b[d];
    }
}

// ---------------------------------------------------------------------------
// Router part 1: partial column sums of x over T (x.mean(1) numerator).
// grid (B, 3, 8), block 256. part layout [B][8][768]
// ---------------------------------------------------------------------------
__global__ __launch_bounds__(256) void mean_part_kernel(
    const float* __restrict__ x, float* __restrict__ part)
{
    int b = blockIdx.x, dseg = blockIdx.y, rc = blockIdx.z;
    int d = dseg * 256 + threadIdx.x;
    const float* xb = x + (long long)b * TT * DD;
    float s = 0.f;
    int r0 = rc * 64;
    for (int r = r0; r < r0 + 64; ++r) s += xb[(long long)r * DD + d];
    part[((long long)b * 8 + rc) * DD + d] = s;
}

// ---------------------------------------------------------------------------
// Router part 2: mean -> gelu(mean@W1^T+b1) -> logits -> segment argmax.
// grid (B), block 128. idx[0..7]=idx_s, idx[8..15]=idx_t
// ---------------------------------------------------------------------------
__global__ __launch_bounds__(128) void router_kernel(
    const float* __restrict__ part, const float* __restrict__ w1,
    const float* __restrict__ b1, const float* __restrict__ w2,
    const float* __restrict__ b2, int* __restrict__ idx)
{
    int b = blockIdx.x, t = threadIdx.x;
    __shared__ float xm[DD];
    __shared__ float h[128];
    __shared__ float logits[8];
    for (int i = t; i < DD; i += 128) {
        float s = 0.f;
        for (int rc = 0; rc < 8; ++rc) s += part[((long long)b * 8 + rc) * DD + i];
        xm[i] = s * (1.0f / TT);
    }
    __syncthreads();
    {
        float s = b1[t];
        const float* w = w1 + (long long)t * DD;
        for (int d = 0; d < DD; ++d) s += xm[d] * w[d];
        h[t] = gelu_exact(s);
    }
    __syncthreads();
    if (t < 8) {
        float s = b2[t];
        const float* w = w2 + t * 128;
        for (int d = 0; d < 128; ++d) s += h[d] * w[d];
        logits[t] = s;
    }
    __syncthreads();
    if (t == 0) {
        int bsix = 0;
        for (int i = 1; i < 4; i++) if (logits[i] > logits[bsix]) bsix = i;
        int btix = 4;
        for (int i = 5; i < 8; i++) if (logits[i] > logits[btix]) btix = i;
        idx[b] = bsix;
        idx[b + BB] = btix - 4;
    }
}

// ---------------------------------------------------------------------------
static void run_gemm(hipStream_t stream, int transb,
    const float* A, long long sAb, long long sAh, int lda,
    const float* Bmat, long long sBb, long long sBh, int ldb,
    const int* bidx, long long sBexp,
    float* C, long long sCb, long long sCh, int ldc,
    const float* bias, long long sBiasExp,
    const float* resid, long long sResB, int ldr,
    float alpha, int act, int M, int N, int K, int Hd, int batchB)
{
    dim3 grid((N + 63) / 64, (M + 63) / 64, batchB * Hd);
    if (transb)
        gemm_kernel<1><<<grid, 256, 0, stream>>>(A, sAb, sAh, lda, Bmat, sBb, sBh, ldb,
            bidx, sBexp, C, sCb, sCh, ldc, bias, sBiasExp, resid, sResB, ldr,
            alpha, act, M, N, K, Hd);
    else
        gemm_kernel<0><<<grid, 256, 0, stream>>>(A, sAb, sAh, lda, Bmat, sBb, sBh, ldb,
            bidx, sBexp, C, sCb, sCh, ldc, bias, sBiasExp, resid, sResB, ldr,
            alpha, act, M, N, K, Hd);
}

extern "C" void kernel_launch(void* const* d_in, const int* in_sizes, int n_in,
                              void* d_out, int out_size, void* d_ws, size_t ws_size,
                              hipStream_t stream)
{
    const float* x       = (const float*)d_in[0];
    const float* rw1     = (const float*)d_in[1];
    const float* rb1     = (const float*)d_in[2];
    const float* rw2     = (const float*)d_in[3];
    const float* rb2     = (const float*)d_in[4];
    const float* gs      = (const float*)d_in[5];
    const float* bs      = (const float*)d_in[6];
    const float* gt      = (const float*)d_in[7];
    const float* btt     = (const float*)d_in[8];
    const float* gm      = (const float*)d_in[9];
    const float* bm      = (const float*)d_in[10];
    const float* sp_wqkv = (const float*)d_in[11];
    const float* sp_bqkv = (const float*)d_in[12];
    const float* sp_wo   = (const float*)d_in[13];
    const float* sp_bo   = (const float*)d_in[14];
    const float* tp_wq   = (const float*)d_in[15];
    const float* tp_bq   = (const float*)d_in[16];
    const float* tp_wk   = (const float*)d_in[17];
    const float* tp_bk   = (const float*)d_in[18];
    const float* tp_wv   = (const float*)d_in[19];
    const float* tp_bv   = (const float*)d_in[20];
    const float* tp_wo   = (const float*)d_in[21];
    const float* tp_bo   = (const float*)d_in[22];
    const float* c_wqkv  = (const float*)d_in[23];
    const float* c_bqkv  = (const float*)d_in[24];
    const float* c_wo    = (const float*)d_in[25];
    const float* c_bo    = (const float*)d_in[26];
    const float* m_w1    = (const float*)d_in[27];
    const float* m_b1    = (const float*)d_in[28];
    const float* m_w2    = (const float*)d_in[29];
    const float* m_b2    = (const float*)d_in[30];
    float* out = (float*)d_out;

    float* ws = (float*)d_ws;
    size_t o = 0;
    float* part  = ws + o; o += (size_t)BB * 8 * DD;
    int*   idx   = (int*)(ws + o); o += 16;
    float* xn    = ws + o; o += (size_t)4096 * DD;   // LN outputs (xn_s, then xt, then x1)
    float* tmp1  = ws + o; o += (size_t)4096 * DD;   // attention outputs
    float* tmp2  = ws + o; o += (size_t)4096 * DD;   // LN for mlp
    float* soutb = ws + o; o += (size_t)4096 * DD;   // spatial_out
    float* toutb = ws + o; o += (size_t)4096 * DD;   // temporal_out
    float* x1b   = ws + o; o += (size_t)4096 * DD;   // x + fused
    float* qkvb  = ws + o; o += (size_t)4096 * 2304; // q|k|v packed, ldc=2304
    float* Sb    = ws + o; o += (size_t)64 * TT * TT; // scores; aliased as mlp hidden y

    int* idx_s = idx;
    int* idx_t = idx + BB;

    const long long sTD  = (long long)TT * DD;       // 512*768
    const long long sT3D = (long long)TT * 3 * DD;   // 512*2304
    const long long sSb  = (long long)HH * TT * TT;  // per-sample score stride
    const long long sSh  = (long long)TT * TT;       // per-head score stride
    const float qk_scale = 1.0f / sqrtf((float)HDIM);

    // ---- router ----
    mean_part_kernel<<<dim3(BB, 3, 8), 256, 0, stream>>>(x, part);
    router_kernel<<<BB, 128, 0, stream>>>(part, rw1, rb1, rw2, rb2, idx);

    // ---- spatial branch ----
    ln_kernel<<<4096, 256, 0, stream>>>(x, gs, bs, xn);
    // qkv = xn @ sp_wqkv[idx_s]^T + sp_bqkv[idx_s]
    run_gemm(stream, 1, xn, sTD, 0, DD, sp_wqkv, 0, 0, DD, idx_s, (long long)3 * DD * DD,
             qkvb, sT3D, 0, 3 * DD, sp_bqkv, 3 * DD, nullptr, 0, 0,
             1.0f, 0, TT, 3 * DD, DD, 1, BB);
    // S = scale * Q K^T  per (b,h)
    run_gemm(stream, 1, qkvb, sT3D, HDIM, 3 * DD, qkvb + DD, sT3D, HDIM, 3 * DD, nullptr, 0,
             Sb, sSb, sSh, TT, nullptr, 0, nullptr, 0, 0,
             qk_scale, 0, TT, TT, HDIM, HH, BB);
    softmax_kernel<<<dim3(TT, BB * HH), 256, 0, stream>>>(Sb, 0);
    // O = P V
    run_gemm(stream, 0, Sb, sSb, sSh, TT, qkvb + 2 * DD, sT3D, HDIM, 3 * DD, nullptr, 0,
             tmp1, sTD, HDIM, DD, nullptr, 0, nullptr, 0, 0,
             1.0f, 0, TT, HDIM, TT, HH, BB);
    // spatial_out = O @ sp_wo[idx_s]^T + sp_bo[idx_s]
    run_gemm(stream, 1, tmp1, sTD, 0, DD, sp_wo, 0, 0, DD, idx_s, (long long)DD * DD,
             soutb, sTD, 0, DD, sp_bo, DD, nullptr, 0, 0,
             1.0f, 0, TT, DD, DD, 1, BB);

    // ---- temporal branch ----
    ln_kernel<<<4096, 256, 0, stream>>>(x, gt, btt, xn);
    run_gemm(stream, 1, xn, sTD, 0, DD, tp_wq, 0, 0, DD, idx_t, (long long)DD * DD,
             qkvb, sT3D, 0, 3 * DD, tp_bq, DD, nullptr, 0, 0,
             1.0f, 0, TT, DD, DD, 1, BB);
    run_gemm(stream, 1, xn, sTD, 0, DD, tp_wk, 0, 0, DD, idx_t, (long long)DD * DD,
             qkvb + DD, sT3D, 0, 3 * DD, tp_bk, DD, nullptr, 0, 0,
             1.0f, 0, TT, DD, DD, 1, BB);
    run_gemm(stream, 1, xn, sTD, 0, DD, tp_wv, 0, 0, DD, idx_t, (long long)DD * DD,
             qkvb + 2 * DD, sT3D, 0, 3 * DD, tp_bv, DD, nullptr, 0, 0,
             1.0f, 0, TT, DD, DD, 1, BB);
    run_gemm(stream, 1, qkvb, sT3D, HDIM, 3 * DD, qkvb + DD, sT3D, HDIM, 3 * DD, nullptr, 0,
             Sb, sSb, sSh, TT, nullptr, 0, nullptr, 0, 0,
             qk_scale, 0, TT, TT, HDIM, HH, BB);
    softmax_kernel<<<dim3(TT, BB * HH), 256, 0, stream>>>(Sb, 1);
    run_gemm(stream, 0, Sb, sSb, sSh, TT, qkvb + 2 * DD, sT3D, HDIM, 3 * DD, nullptr, 0,
             tmp1, sTD, HDIM, DD, nullptr, 0, nullptr, 0, 0,
             1.0f, 0, TT, HDIM, TT, HH, BB);
    // temporal_out = xt + O @ tp_wo[idx_t]^T + tp_bo[idx_t]
    run_gemm(stream, 1, tmp1, sTD, 0, DD, tp_wo, 0, 0, DD, idx_t, (long long)DD * DD,
             toutb, sTD, 0, DD, tp_bo, DD, xn, sTD, DD,
             1.0f, 0, TT, DD, DD, 1, BB);

    // ---- cross attention ----
    // cq = spatial_out @ Wq^T + bq  (rows 0..768 of cross_wqkv)
    run_gemm(stream, 1, soutb, sTD, 0, DD, c_wqkv, 0, 0, DD, nullptr, 0,
             qkvb, sT3D, 0, 3 * DD, c_bqkv, 0, nullptr, 0, 0,
             1.0f, 0, TT, DD, DD, 1, BB);
    // ck|cv = temporal_out @ Wkv^T + bkv (rows 768..2304), N=1536
    run_gemm(stream, 1, toutb, sTD, 0, DD, c_wqkv + (long long)DD * DD, 0, 0, DD, nullptr, 0,
             qkvb + DD, sT3D, 0, 3 * DD, c_bqkv + DD, 0, nullptr, 0, 0,
             1.0f, 0, TT, 2 * DD, DD, 1, BB);
    run_gemm(stream, 1, qkvb, sT3D, HDIM, 3 * DD, qkvb + DD, sT3D, HDIM, 3 * DD, nullptr, 0,
             Sb, sSb, sSh, TT, nullptr, 0, nullptr, 0, 0,
             qk_scale, 0, TT, TT, HDIM, HH, BB);
    softmax_kernel<<<dim3(TT, BB * HH), 256, 0, stream>>>(Sb, 0);
    run_gemm(stream, 0, Sb, sSb, sSh, TT, qkvb + 2 * DD, sT3D, HDIM, 3 * DD, nullptr, 0,
             tmp1, sTD, HDIM, DD, nullptr, 0, nullptr, 0, 0,
             1.0f, 0, TT, HDIM, TT, HH, BB);
    // x1 = x + (fused_attn @ cross_wo^T + cross_bo)
    run_gemm(stream, 1, tmp1, sTD, 0, DD, c_wo, 0, 0, DD, nullptr, 0,
             x1b, sTD, 0, DD, c_bo, 0, x, sTD, DD,
             1.0f, 0, TT, DD, DD, 1, BB);

    // ---- MLP ----
    ln_kernel<<<4096, 256, 0, stream>>>(x1b, gm, bm, tmp2);
    // y = gelu(ln @ mlp_w1^T + b1)  -> Sb (aliased as y, 4096x3072)
    run_gemm(stream, 1, tmp2, sTD, 0, DD, m_w1, 0, 0, DD, nullptr, 0,
             Sb, (long long)TT * 4 * DD, 0, 4 * DD, m_b1, 0, nullptr, 0, 0,
             1.0f, 1, TT, 4 * DD, DD, 1, BB);
    // out = x1 + y @ mlp_w2^T + b2
    run_gemm(stream, 1, Sb, (long long)TT * 4 * DD, 0, 4 * DD, m_w2, 0, 0, 4 * DD, nullptr, 0,
             out, sTD, 0, DD, m_b2, 0, x1b, sTD, DD,
             1.0f, 0, TT, DD, 4 * DD, 1, BB);
}